// Round 1
// baseline (1470.622 us; speedup 1.0000x reference)
//
#include <hip/hip_runtime.h>

// db2 filters, pre-flipped (cross-correlation form used by ptwt)
#define LO0 0.4829629131445341f
#define LO1 0.8365163037378079f
#define LO2 0.22414386804185735f
#define LO3 (-0.12940952255092145f)
#define HI0 (-0.12940952255092145f)
#define HI1 (-0.22414386804185735f)
#define HI2 0.8365163037378079f
#define HI3 (-0.4829629131445341f)

__device__ __forceinline__ int reflect_idx(int r, int n) {
    if (r < 0) r = -r;
    else if (r >= n) r = 2 * n - 2 - r;
    return r;
}

// Kernel 1: d = p - t on the fly, then one separable DWT step.
// in: p,t [NB, H, W]; out: [NB, 4, HO, WO]
__global__ void k_diff_dwt(const float* __restrict__ p, const float* __restrict__ t,
                           float* __restrict__ out, int H, int W, int HO, int WO) {
    int j = blockIdx.x * blockDim.x + threadIdx.x;
    int i = blockIdx.y * blockDim.y + threadIdx.y;
    int img = blockIdx.z;
    if (i >= HO || j >= WO) return;
    const float lo[4] = {LO0, LO1, LO2, LO3};
    const float hi[4] = {HI0, HI1, HI2, HI3};
    const float* pp = p + (size_t)img * H * W;
    const float* tt = t + (size_t)img * H * W;
    int cols[4], rows[4];
#pragma unroll
    for (int v = 0; v < 4; ++v) cols[v] = reflect_idx(2 * j + v - 2, W);
#pragma unroll
    for (int u = 0; u < 4; ++u) rows[u] = reflect_idx(2 * i + u - 2, H);
    float slo[4], shi[4];
#pragma unroll
    for (int u = 0; u < 4; ++u) {
        float a = 0.f, b = 0.f;
        const float* pr = pp + (size_t)rows[u] * W;
        const float* tr = tt + (size_t)rows[u] * W;
#pragma unroll
        for (int v = 0; v < 4; ++v) {
            float x = pr[cols[v]] - tr[cols[v]];
            a += lo[v] * x;
            b += hi[v] * x;
        }
        slo[u] = a;
        shi[u] = b;
    }
    float o0 = 0.f, o1 = 0.f, o2 = 0.f, o3 = 0.f;
#pragma unroll
    for (int u = 0; u < 4; ++u) {
        o0 += lo[u] * slo[u];  // height lo, width lo -> 'a'
        o1 += hi[u] * slo[u];  // height hi, width lo -> 'h'
        o2 += lo[u] * shi[u];  // height lo, width hi -> 'v'
        o3 += hi[u] * shi[u];  // height hi, width hi -> 'd'
    }
    size_t plane = (size_t)HO * WO;
    size_t base = ((size_t)img * 4) * plane + (size_t)i * WO + j;
    out[base] = o0;
    out[base + plane] = o1;
    out[base + 2 * plane] = o2;
    out[base + 3 * plane] = o3;
}

// Kernel 2: plain separable DWT step on a batch of independent images.
// in: [NB, H, W]; out: [NB, 4, HO, WO]
__global__ void k_dwt(const float* __restrict__ in, float* __restrict__ out,
                      int H, int W, int HO, int WO) {
    int j = blockIdx.x * blockDim.x + threadIdx.x;
    int i = blockIdx.y * blockDim.y + threadIdx.y;
    int img = blockIdx.z;
    if (i >= HO || j >= WO) return;
    const float lo[4] = {LO0, LO1, LO2, LO3};
    const float hi[4] = {HI0, HI1, HI2, HI3};
    const float* pp = in + (size_t)img * H * W;
    int cols[4], rows[4];
#pragma unroll
    for (int v = 0; v < 4; ++v) cols[v] = reflect_idx(2 * j + v - 2, W);
#pragma unroll
    for (int u = 0; u < 4; ++u) rows[u] = reflect_idx(2 * i + u - 2, H);
    float slo[4], shi[4];
#pragma unroll
    for (int u = 0; u < 4; ++u) {
        float a = 0.f, b = 0.f;
        const float* pr = pp + (size_t)rows[u] * W;
#pragma unroll
        for (int v = 0; v < 4; ++v) {
            float x = pr[cols[v]];
            a += lo[v] * x;
            b += hi[v] * x;
        }
        slo[u] = a;
        shi[u] = b;
    }
    float o0 = 0.f, o1 = 0.f, o2 = 0.f, o3 = 0.f;
#pragma unroll
    for (int u = 0; u < 4; ++u) {
        o0 += lo[u] * slo[u];
        o1 += hi[u] * slo[u];
        o2 += lo[u] * shi[u];
        o3 += hi[u] * shi[u];
    }
    size_t plane = (size_t)HO * WO;
    size_t base = ((size_t)img * 4) * plane + (size_t)i * WO + j;
    out[base] = o0;
    out[base + plane] = o1;
    out[base + 2 * plane] = o2;
    out[base + 3 * plane] = o3;
}

// Kernel 3: final DWT step fused with weighted sum-of-squares reduction.
// in: [NB, H, W] where NB = b*16; leaf index = (img%16)*4 + f; weight 0.5 for leaf 0.
__global__ void k_dwt_sq(const float* __restrict__ in, float* __restrict__ out_sum,
                         int H, int W, int HO, int WO, float inv_den) {
    int j = blockIdx.x * blockDim.x + threadIdx.x;
    int i = blockIdx.y * blockDim.y + threadIdx.y;
    int img = blockIdx.z;
    float local = 0.f;
    if (i < HO && j < WO) {
        const float lo[4] = {LO0, LO1, LO2, LO3};
        const float hi[4] = {HI0, HI1, HI2, HI3};
        const float* pp = in + (size_t)img * H * W;
        int cols[4], rows[4];
#pragma unroll
        for (int v = 0; v < 4; ++v) cols[v] = reflect_idx(2 * j + v - 2, W);
#pragma unroll
        for (int u = 0; u < 4; ++u) rows[u] = reflect_idx(2 * i + u - 2, H);
        float slo[4], shi[4];
#pragma unroll
        for (int u = 0; u < 4; ++u) {
            float a = 0.f, b = 0.f;
            const float* pr = pp + (size_t)rows[u] * W;
#pragma unroll
            for (int v = 0; v < 4; ++v) {
                float x = pr[cols[v]];
                a += lo[v] * x;
                b += hi[v] * x;
            }
            slo[u] = a;
            shi[u] = b;
        }
        float o0 = 0.f, o1 = 0.f, o2 = 0.f, o3 = 0.f;
#pragma unroll
        for (int u = 0; u < 4; ++u) {
            o0 += lo[u] * slo[u];
            o1 += hi[u] * slo[u];
            o2 += lo[u] * shi[u];
            o3 += hi[u] * shi[u];
        }
        int c2 = img & 15;  // level-2 band of this image
        float w0 = (c2 == 0) ? 0.5f : 1.0f;  // leaf 0 = (c2==0, f==0)
        local = w0 * o0 * o0 + o1 * o1 + o2 * o2 + o3 * o3;
        local *= inv_den;
    }
    // block reduction: 256 threads = 4 waves
#pragma unroll
    for (int off = 32; off > 0; off >>= 1) local += __shfl_down(local, off, 64);
    __shared__ float wsum[4];
    int tid = threadIdx.y * blockDim.x + threadIdx.x;
    int wave = tid >> 6;
    if ((tid & 63) == 0) wsum[wave] = local;
    __syncthreads();
    if (tid == 0) {
        float s = wsum[0] + wsum[1] + wsum[2] + wsum[3];
        atomicAdd(out_sum, s);
    }
}

extern "C" void kernel_launch(void* const* d_in, const int* in_sizes, int n_in,
                              void* d_out, int out_size, void* d_ws, size_t ws_size,
                              hipStream_t stream) {
    const float* preds = (const float*)d_in[0];
    const float* targets = (const float*)d_in[1];
    float* out = (float*)d_out;

    const int NB = 192;                    // 64*3 independent images
    const int H0 = 512, W0 = 512;
    const int H1 = 257, W1 = 257;
    const int H2 = 130, W2 = 130;
    const int H3 = 66, W3 = 66;

    const size_t l1_per_img = (size_t)4 * H1 * W1 * sizeof(float);
    const size_t l2_per_img = (size_t)16 * H2 * W2 * sizeof(float);
    const size_t per_img = l1_per_img + l2_per_img;

    int B = (int)(ws_size / per_img);
    if (B > NB) B = NB;
    if (B < 1) B = 1;

    hipMemsetAsync(d_out, 0, sizeof(float), stream);

    const float inv_den = 1.0f / (192.0f * 66.0f * 66.0f);
    dim3 blk(16, 16);

    for (int s0 = 0; s0 < NB; s0 += B) {
        int b = (NB - s0 < B) ? (NB - s0) : B;
        float* l1 = (float*)d_ws;
        float* l2 = (float*)((char*)d_ws + l1_per_img * (size_t)b);

        k_diff_dwt<<<dim3((W1 + 15) / 16, (H1 + 15) / 16, b), blk, 0, stream>>>(
            preds + (size_t)s0 * H0 * W0, targets + (size_t)s0 * H0 * W0,
            l1, H0, W0, H1, W1);

        k_dwt<<<dim3((W2 + 15) / 16, (H2 + 15) / 16, b * 4), blk, 0, stream>>>(
            l1, l2, H1, W1, H2, W2);

        k_dwt_sq<<<dim3((W3 + 15) / 16, (H3 + 15) / 16, b * 16), blk, 0, stream>>>(
            l2, out, H2, W2, H3, W3, inv_den);
    }
}

// Round 2
// 622.942 us; speedup vs baseline: 2.3608x; 2.3608x over previous
//
#include <hip/hip_runtime.h>

// db2 filters, pre-flipped (cross-correlation form used by ptwt)
#define LO0 0.4829629131445341f
#define LO1 0.8365163037378079f
#define LO2 0.22414386804185735f
#define LO3 (-0.12940952255092145f)
#define HI0 (-0.12940952255092145f)
#define HI1 (-0.22414386804185735f)
#define HI2 0.8365163037378079f
#define HI3 (-0.4829629131445341f)

__device__ __forceinline__ int reflect_idx(int r, int n) {
    if (r < 0) r = -r;
    else if (r >= n) r = 2 * n - 2 - r;
    return r;
}

// Kernel 1: d = p - t on the fly, then one separable DWT step.
// in: p,t [NB, H, W]; out: [NB, 4, HO, WO]
__global__ void k_diff_dwt(const float* __restrict__ p, const float* __restrict__ t,
                           float* __restrict__ out, int H, int W, int HO, int WO) {
    int j = blockIdx.x * blockDim.x + threadIdx.x;
    int i = blockIdx.y * blockDim.y + threadIdx.y;
    int img = blockIdx.z;
    if (i >= HO || j >= WO) return;
    const float lo[4] = {LO0, LO1, LO2, LO3};
    const float hi[4] = {HI0, HI1, HI2, HI3};
    const float* pp = p + (size_t)img * H * W;
    const float* tt = t + (size_t)img * H * W;
    int cols[4], rows[4];
#pragma unroll
    for (int v = 0; v < 4; ++v) cols[v] = reflect_idx(2 * j + v - 2, W);
#pragma unroll
    for (int u = 0; u < 4; ++u) rows[u] = reflect_idx(2 * i + u - 2, H);
    float slo[4], shi[4];
#pragma unroll
    for (int u = 0; u < 4; ++u) {
        float a = 0.f, b = 0.f;
        const float* pr = pp + (size_t)rows[u] * W;
        const float* tr = tt + (size_t)rows[u] * W;
#pragma unroll
        for (int v = 0; v < 4; ++v) {
            float x = pr[cols[v]] - tr[cols[v]];
            a += lo[v] * x;
            b += hi[v] * x;
        }
        slo[u] = a;
        shi[u] = b;
    }
    float o0 = 0.f, o1 = 0.f, o2 = 0.f, o3 = 0.f;
#pragma unroll
    for (int u = 0; u < 4; ++u) {
        o0 += lo[u] * slo[u];  // height lo, width lo -> 'a'
        o1 += hi[u] * slo[u];  // height hi, width lo -> 'h'
        o2 += lo[u] * shi[u];  // height lo, width hi -> 'v'
        o3 += hi[u] * shi[u];  // height hi, width hi -> 'd'
    }
    size_t plane = (size_t)HO * WO;
    size_t base = ((size_t)img * 4) * plane + (size_t)i * WO + j;
    out[base] = o0;
    out[base + plane] = o1;
    out[base + 2 * plane] = o2;
    out[base + 3 * plane] = o3;
}

// Kernel 2: plain separable DWT step on a batch of independent images.
// in: [NB, H, W]; out: [NB, 4, HO, WO]
__global__ void k_dwt(const float* __restrict__ in, float* __restrict__ out,
                      int H, int W, int HO, int WO) {
    int j = blockIdx.x * blockDim.x + threadIdx.x;
    int i = blockIdx.y * blockDim.y + threadIdx.y;
    int img = blockIdx.z;
    if (i >= HO || j >= WO) return;
    const float lo[4] = {LO0, LO1, LO2, LO3};
    const float hi[4] = {HI0, HI1, HI2, HI3};
    const float* pp = in + (size_t)img * H * W;
    int cols[4], rows[4];
#pragma unroll
    for (int v = 0; v < 4; ++v) cols[v] = reflect_idx(2 * j + v - 2, W);
#pragma unroll
    for (int u = 0; u < 4; ++u) rows[u] = reflect_idx(2 * i + u - 2, H);
    float slo[4], shi[4];
#pragma unroll
    for (int u = 0; u < 4; ++u) {
        float a = 0.f, b = 0.f;
        const float* pr = pp + (size_t)rows[u] * W;
#pragma unroll
        for (int v = 0; v < 4; ++v) {
            float x = pr[cols[v]];
            a += lo[v] * x;
            b += hi[v] * x;
        }
        slo[u] = a;
        shi[u] = b;
    }
    float o0 = 0.f, o1 = 0.f, o2 = 0.f, o3 = 0.f;
#pragma unroll
    for (int u = 0; u < 4; ++u) {
        o0 += lo[u] * slo[u];
        o1 += hi[u] * slo[u];
        o2 += lo[u] * shi[u];
        o3 += hi[u] * shi[u];
    }
    size_t plane = (size_t)HO * WO;
    size_t base = ((size_t)img * 4) * plane + (size_t)i * WO + j;
    out[base] = o0;
    out[base + plane] = o1;
    out[base + 2 * plane] = o2;
    out[base + 3 * plane] = o3;
}

// Kernel 3: final DWT step fused with weighted sum-of-squares reduction.
// Persistent grid-stride version: few blocks, local accumulation, ONE atomic
// per block (previous version did 76,800 same-address atomics -> 981 us).
// in: [nplanes, H, W] where plane index = img*16 + c1*4 + c2; leaf 0 has
// weight 0.5 and corresponds to (plane%16)==0 && f==0.
__global__ void k_dwt_sq(const float* __restrict__ in, float* __restrict__ out_sum,
                         int nplanes, int H, int W, int HO, int WO, float inv_den) {
    const float lo[4] = {LO0, LO1, LO2, LO3};
    const float hi[4] = {HI0, HI1, HI2, HI3};
    const int total = nplanes * HO * WO;
    float local = 0.f;
    for (int idx = blockIdx.x * blockDim.x + threadIdx.x; idx < total;
         idx += gridDim.x * blockDim.x) {
        int j = idx % WO;
        int rem = idx / WO;
        int i = rem % HO;
        int img = rem / HO;
        const float* pp = in + (size_t)img * H * W;
        int cols[4], rows[4];
#pragma unroll
        for (int v = 0; v < 4; ++v) cols[v] = reflect_idx(2 * j + v - 2, W);
#pragma unroll
        for (int u = 0; u < 4; ++u) rows[u] = reflect_idx(2 * i + u - 2, H);
        float slo[4], shi[4];
#pragma unroll
        for (int u = 0; u < 4; ++u) {
            float a = 0.f, b = 0.f;
            const float* pr = pp + (size_t)rows[u] * W;
#pragma unroll
            for (int v = 0; v < 4; ++v) {
                float x = pr[cols[v]];
                a += lo[v] * x;
                b += hi[v] * x;
            }
            slo[u] = a;
            shi[u] = b;
        }
        float o0 = 0.f, o1 = 0.f, o2 = 0.f, o3 = 0.f;
#pragma unroll
        for (int u = 0; u < 4; ++u) {
            o0 += lo[u] * slo[u];
            o1 += hi[u] * slo[u];
            o2 += lo[u] * shi[u];
            o3 += hi[u] * shi[u];
        }
        float w0 = ((img & 15) == 0) ? 0.5f : 1.0f;
        local += w0 * o0 * o0 + o1 * o1 + o2 * o2 + o3 * o3;
    }
    local *= inv_den;
    // block reduction: 256 threads = 4 waves
#pragma unroll
    for (int off = 32; off > 0; off >>= 1) local += __shfl_down(local, off, 64);
    __shared__ float wsum[4];
    int tid = threadIdx.x;
    int wave = tid >> 6;
    if ((tid & 63) == 0) wsum[wave] = local;
    __syncthreads();
    if (tid == 0) {
        float s = wsum[0] + wsum[1] + wsum[2] + wsum[3];
        atomicAdd(out_sum, s);
    }
}

extern "C" void kernel_launch(void* const* d_in, const int* in_sizes, int n_in,
                              void* d_out, int out_size, void* d_ws, size_t ws_size,
                              hipStream_t stream) {
    const float* preds = (const float*)d_in[0];
    const float* targets = (const float*)d_in[1];
    float* out = (float*)d_out;

    const int NB = 192;                    // 64*3 independent images
    const int H0 = 512, W0 = 512;
    const int H1 = 257, W1 = 257;
    const int H2 = 130, W2 = 130;
    const int H3 = 66, W3 = 66;

    const size_t l1_per_img = (size_t)4 * H1 * W1 * sizeof(float);
    const size_t l2_per_img = (size_t)16 * H2 * W2 * sizeof(float);
    const size_t per_img = l1_per_img + l2_per_img;

    int B = (int)(ws_size / per_img);
    if (B > NB) B = NB;
    if (B < 1) B = 1;

    hipMemsetAsync(d_out, 0, sizeof(float), stream);

    const float inv_den = 1.0f / (192.0f * 66.0f * 66.0f);
    dim3 blk(16, 16);

    for (int s0 = 0; s0 < NB; s0 += B) {
        int b = (NB - s0 < B) ? (NB - s0) : B;
        float* l1 = (float*)d_ws;
        float* l2 = (float*)((char*)d_ws + l1_per_img * (size_t)b);

        k_diff_dwt<<<dim3((W1 + 15) / 16, (H1 + 15) / 16, b), blk, 0, stream>>>(
            preds + (size_t)s0 * H0 * W0, targets + (size_t)s0 * H0 * W0,
            l1, H0, W0, H1, W1);

        k_dwt<<<dim3((W2 + 15) / 16, (H2 + 15) / 16, b * 4), blk, 0, stream>>>(
            l1, l2, H1, W1, H2, W2);

        int nplanes = b * 16;
        int total = nplanes * H3 * W3;
        int nblk = (total + 255) / 256;
        if (nblk > 2560) nblk = 2560;
        k_dwt_sq<<<dim3(nblk), dim3(256), 0, stream>>>(
            l2, out, nplanes, H2, W2, H3, W3, inv_den);
    }
}

// Round 3
// 452.548 us; speedup vs baseline: 3.2496x; 1.3765x over previous
//
#include <hip/hip_runtime.h>

// db2 filters, pre-flipped (cross-correlation form used by ptwt)
#define F_LO0 0.4829629131445341f
#define F_LO1 0.8365163037378079f
#define F_LO2 0.22414386804185735f
#define F_LO3 (-0.12940952255092145f)
#define F_HI0 (-0.12940952255092145f)
#define F_HI1 (-0.22414386804185735f)
#define F_HI2 0.8365163037378079f
#define F_HI3 (-0.4829629131445341f)

__device__ __forceinline__ int reflect_idx(int r, int n) {
    if (r < 0) r = -r;
    else if (r >= n) r = 2 * n - 2 - r;
    return r;
}

// 4x4 separable db2 step at one output position: 16 gathers -> 4 band values.
__device__ __forceinline__ void dwt4(const float* __restrict__ src, int stride,
                                     const int* rows, const int* cols,
                                     float& o0, float& o1, float& o2, float& o3) {
    const float lo[4] = {F_LO0, F_LO1, F_LO2, F_LO3};
    const float hi[4] = {F_HI0, F_HI1, F_HI2, F_HI3};
    float slo[4], shi[4];
#pragma unroll
    for (int u = 0; u < 4; ++u) {
        float a = 0.f, b = 0.f;
        const float* sr = src + rows[u] * stride;
#pragma unroll
        for (int v = 0; v < 4; ++v) {
            float x = sr[cols[v]];
            a += lo[v] * x;
            b += hi[v] * x;
        }
        slo[u] = a;
        shi[u] = b;
    }
    o0 = o1 = o2 = o3 = 0.f;
#pragma unroll
    for (int u = 0; u < 4; ++u) {
        o0 += lo[u] * slo[u];  // h-lo w-lo 'a'
        o1 += hi[u] * slo[u];  // h-hi w-lo 'h'
        o2 += lo[u] * shi[u];  // h-lo w-hi 'v'
        o3 += hi[u] * shi[u];  // h-hi w-hi 'd'
    }
}

// Fully fused 3-level WPT + weighted squared-sum reduction.
// One block = one 8x8 tile of the level-3 (66x66) output for one image.
// LDS: input diff tile 78x78 (aliased with 16x18x18 L2), plus 4x38x38 L1.
__global__ void __launch_bounds__(256) k_wpt_fused(
    const float* __restrict__ p, const float* __restrict__ t,
    float* __restrict__ out_sum, float inv_den) {
    constexpr int N0 = 512, N1 = 257, N2 = 130, N3 = 66;
    constexpr int T0 = 78, T1 = 38, T2 = 18;

    __shared__ float s_buf[T0 * T0];       // stage0: diff input; stage2+: L2 (16*324=5184 <= 6084)
    __shared__ float s_l1[4 * T1 * T1];    // 4 L1 bands

    // XCD-chunked swizzle: 15552 blocks = 8 * 1944; consecutive tiles/images share an XCD L2.
    int bid = blockIdx.x;
    int swz = (bid & 7) * (int)(gridDim.x >> 3) + (bid >> 3);
    int img = swz / 81;
    int tt = swz - img * 81;
    int A = (tt / 9) * 8;  // L3 row base
    int B = (tt % 9) * 8;  // L3 col base

    const int tid = threadIdx.x;
    const float* __restrict__ pimg = p + (size_t)img * (N0 * N0);
    const float* __restrict__ timg = t + (size_t)img * (N0 * N0);

    // unclamped tile origins per level
    const int O0r = 8 * A - 14, O0c = 8 * B - 14;
    const int O1r = 4 * A - 6, O1c = 4 * B - 6;
    const int O2r = 2 * A - 2, O2c = 2 * B - 2;

    // ---- stage 0: load p-t tile into LDS (clamped to valid global range) ----
    {
        int rlo = max(0, O0r), rhi = min(N0 - 1, O0r + T0 - 1);
        int clo = max(0, O0c), chi = min(N0 - 1, O0c + T0 - 1);
        int nc = chi - clo + 1;
        int tot = (rhi - rlo + 1) * nc;
        int r = rlo + tid / nc;
        int c = clo + tid % nc;
        for (int e = tid; e < tot; e += 256) {
            int g = r * N0 + c;
            s_buf[(r - O0r) * T0 + (c - O0c)] = pimg[g] - timg[g];
            c += 256;
            while (c > chi) { c -= nc; ++r; }
        }
    }
    __syncthreads();

    // ---- stage 1: L1 = DWT(diff), 4 bands in s_l1 ----
    {
        int rlo = max(0, O1r), rhi = min(N1 - 1, O1r + T1 - 1);
        int clo = max(0, O1c), chi = min(N1 - 1, O1c + T1 - 1);
        int nc = chi - clo + 1;
        int tot = (rhi - rlo + 1) * nc;
        int r1 = rlo + tid / nc;
        int c1 = clo + tid % nc;
        for (int e = tid; e < tot; e += 256) {
            int rows[4], cols[4];
#pragma unroll
            for (int u = 0; u < 4; ++u) rows[u] = reflect_idx(2 * r1 - 2 + u, N0) - O0r;
#pragma unroll
            for (int v = 0; v < 4; ++v) cols[v] = reflect_idx(2 * c1 - 2 + v, N0) - O0c;
            float o0, o1, o2, o3;
            dwt4(s_buf, T0, rows, cols, o0, o1, o2, o3);
            int slot = (r1 - O1r) * T1 + (c1 - O1c);
            s_l1[slot] = o0;
            s_l1[T1 * T1 + slot] = o1;
            s_l1[2 * T1 * T1 + slot] = o2;
            s_l1[3 * T1 * T1 + slot] = o3;
            c1 += 256;
            while (c1 > chi) { c1 -= nc; ++r1; }
        }
    }
    __syncthreads();

    // ---- stage 2: L2 = DWT(L1), 16 bands written into s_buf (input dead now) ----
    {
        int rlo = max(0, O2r), rhi = min(N2 - 1, O2r + T2 - 1);
        int clo = max(0, O2c), chi = min(N2 - 1, O2c + T2 - 1);
        int nc = chi - clo + 1;
        int per = (rhi - rlo + 1) * nc;
        int tot = 4 * per;
        for (int e = tid; e < tot; e += 256) {
            int band = e / per;
            int rem = e - band * per;
            int r2 = rlo + rem / nc;
            int c2 = clo + rem % nc;
            int rows[4], cols[4];
#pragma unroll
            for (int u = 0; u < 4; ++u) rows[u] = reflect_idx(2 * r2 - 2 + u, N1) - O1r;
#pragma unroll
            for (int v = 0; v < 4; ++v) cols[v] = reflect_idx(2 * c2 - 2 + v, N1) - O1c;
            float o0, o1, o2, o3;
            dwt4(s_l1 + band * (T1 * T1), T1, rows, cols, o0, o1, o2, o3);
            int slot = (r2 - O2r) * T2 + (c2 - O2c);
            float* dst = s_buf + band * 4 * (T2 * T2);
            dst[slot] = o0;
            dst[T2 * T2 + slot] = o1;
            dst[2 * T2 * T2 + slot] = o2;
            dst[3 * T2 * T2 + slot] = o3;
        }
    }
    __syncthreads();

    // ---- stage 3: L3 = DWT(L2), square + weight + accumulate ----
    float local = 0.f;
    for (int e = tid; e < 16 * 64; e += 256) {
        int b2 = e >> 6;       // L2 band (= leaf/4)
        int pos = e & 63;
        int i3 = A + (pos >> 3);
        int j3 = B + (pos & 7);
        if (i3 < N3 && j3 < N3) {
            int rows[4], cols[4];
#pragma unroll
            for (int u = 0; u < 4; ++u) rows[u] = reflect_idx(2 * i3 - 2 + u, N2) - O2r;
#pragma unroll
            for (int v = 0; v < 4; ++v) cols[v] = reflect_idx(2 * j3 - 2 + v, N2) - O2c;
            float o0, o1, o2, o3;
            dwt4(s_buf + b2 * (T2 * T2), T2, rows, cols, o0, o1, o2, o3);
            float w0 = (b2 == 0) ? 0.5f : 1.0f;  // leaf 0 = (b2==0, f==0)
            local += w0 * o0 * o0 + o1 * o1 + o2 * o2 + o3 * o3;
        }
    }

    // block reduction: 256 threads = 4 waves, one atomic per block
#pragma unroll
    for (int off = 32; off > 0; off >>= 1) local += __shfl_down(local, off, 64);
    __shared__ float wsum[4];
    int wave = tid >> 6;
    if ((tid & 63) == 0) wsum[wave] = local;
    __syncthreads();
    if (tid == 0) {
        float s = (wsum[0] + wsum[1] + wsum[2] + wsum[3]) * inv_den;
        atomicAdd(out_sum, s);
    }
}

extern "C" void kernel_launch(void* const* d_in, const int* in_sizes, int n_in,
                              void* d_out, int out_size, void* d_ws, size_t ws_size,
                              hipStream_t stream) {
    const float* preds = (const float*)d_in[0];
    const float* targets = (const float*)d_in[1];
    float* out = (float*)d_out;

    hipMemsetAsync(d_out, 0, sizeof(float), stream);

    const float inv_den = 1.0f / (192.0f * 66.0f * 66.0f);
    const int nblk = 192 * 9 * 9;  // 15552, divisible by 8 for the XCD swizzle

    k_wpt_fused<<<dim3(nblk), dim3(256), 0, stream>>>(preds, targets, out, inv_den);
}

// Round 4
// 242.681 us; speedup vs baseline: 6.0599x; 1.8648x over previous
//
#include <hip/hip_runtime.h>

// db2 filters, pre-flipped (cross-correlation form used by ptwt)
#define F_LO0 0.4829629131445341f
#define F_LO1 0.8365163037378079f
#define F_LO2 0.22414386804185735f
#define F_LO3 (-0.12940952255092145f)
#define F_HI0 (-0.12940952255092145f)
#define F_HI1 (-0.22414386804185735f)
#define F_HI2 0.8365163037378079f
#define F_HI3 (-0.4829629131445341f)

__device__ __forceinline__ int reflect_idx(int r, int n) {
    r = (r < 0) ? -r : r;
    r = (r >= n) ? 2 * n - 2 - r : r;
    return r;
}

// Two horizontally-adjacent separable db2 quads (outputs at cols c, c+1).
// Linear gathers: 12 ds_read_b64 total; base must be 8B-aligned (even float idx).
__device__ __forceinline__ void dwt4_pair(const float* __restrict__ s, int base,
                                          int stride, float o[2][4]) {
    float sl[2][4], sh[2][4];
#pragma unroll
    for (int u = 0; u < 4; ++u) {
        const float2 x0 = *(const float2*)(s + base + u * stride);
        const float2 x1 = *(const float2*)(s + base + u * stride + 2);
        const float2 x2 = *(const float2*)(s + base + u * stride + 4);
        sl[0][u] = F_LO0 * x0.x + F_LO1 * x0.y + F_LO2 * x1.x + F_LO3 * x1.y;
        sh[0][u] = F_HI0 * x0.x + F_HI1 * x0.y + F_HI2 * x1.x + F_HI3 * x1.y;
        sl[1][u] = F_LO0 * x1.x + F_LO1 * x1.y + F_LO2 * x2.x + F_LO3 * x2.y;
        sh[1][u] = F_HI0 * x1.x + F_HI1 * x1.y + F_HI2 * x2.x + F_HI3 * x2.y;
    }
#pragma unroll
    for (int q = 0; q < 2; ++q) {
        o[q][0] = F_LO0 * sl[q][0] + F_LO1 * sl[q][1] + F_LO2 * sl[q][2] + F_LO3 * sl[q][3];
        o[q][1] = F_HI0 * sl[q][0] + F_HI1 * sl[q][1] + F_HI2 * sl[q][2] + F_HI3 * sl[q][3];
        o[q][2] = F_LO0 * sh[q][0] + F_LO1 * sh[q][1] + F_LO2 * sh[q][2] + F_LO3 * sh[q][3];
        o[q][3] = F_HI0 * sh[q][0] + F_HI1 * sh[q][1] + F_HI2 * sh[q][2] + F_HI3 * sh[q][3];
    }
}

// Fully fused 3-level WPT + weighted squared-sum reduction, linear-gather version.
// One block = 8x8 tile of the 66x66 level-3 grid for one image.
// Reflection is baked into the stage-0 store; boundary slots of L1/L2 that valid
// gathers touch are patched by a copy pass (edge blocks only). All inner-loop
// gathers are base + immediate-offset float2 reads.
__global__ void __launch_bounds__(256) k_wpt_fused(
    const float* __restrict__ p, const float* __restrict__ t,
    float* __restrict__ out_sum, float inv_den) {
    constexpr int N0 = 512, N1 = 257, N2 = 130, N3 = 66;
    constexpr int S0 = 78;                 // input tile 78x78
    constexpr int S1 = 38, P1 = 38 * 38;   // L1 band tile 38x38
    constexpr int S2 = 20, P2 = 18 * 20;   // L2 band tile 18 rows, stride 20 (pad)

    __shared__ float s_in[78 * 78];        // 6084; reused for L2 (16*360=5760)
    __shared__ float s_l1[4 * P1];         // 5776
    float* const s_l2 = s_in;

    // XCD-chunked swizzle: 15552 = 8 * 1944 (bijective)
    int bid = blockIdx.x;
    int swz = (bid & 7) * (int)(gridDim.x >> 3) + (bid >> 3);
    int img = swz / 81;
    int tt = swz - img * 81;
    int A = (tt / 9) * 8;
    int B = (tt % 9) * 8;

    const int tid = threadIdx.x;
    const size_t ibase = (size_t)img * (N0 * N0);

    const int O0r = 8 * A - 14, O0c = 8 * B - 14;
    const int O1r = 4 * A - 6, O1c = 4 * B - 6;
    const int O2r = 2 * A - 2, O2c = 2 * B - 2;

    const bool edge0 = (O0r < 0) || (O0r + 77 > 511) || (O0c < 0) || (O0c + 77 > 511);
    const bool edge1 = (O1r < 0) || (O1r + 37 > 256) || (O1c < 0) || (O1c + 37 > 256);
    const bool edge2 = (O2r < 0) || (O2r + 17 > 129) || (O2c < 0) || (O2c + 17 > 129);

    // ---- stage 0: pre-reflected diff tile. 78 rows x 39 col-pairs = 3042 units ----
    if (!edge0) {
        const float* prow = p + ibase + (size_t)O0r * N0 + O0c;
        const float* trow = t + ibase + (size_t)O0r * N0 + O0c;
#pragma unroll
        for (int it = 0; it < 12; ++it) {
            int e = it * 256 + tid;
            if (e < 3042) {
                unsigned lr = (unsigned)e / 39u;
                int lc = (int)((unsigned)e - lr * 39u) * 2;
                const float2 pv = *(const float2*)(prow + (size_t)lr * N0 + lc);
                const float2 tv = *(const float2*)(trow + (size_t)lr * N0 + lc);
                *(float2*)(s_in + lr * S0 + lc) = make_float2(pv.x - tv.x, pv.y - tv.y);
            }
        }
    } else {
#pragma unroll
        for (int it = 0; it < 12; ++it) {
            int e = it * 256 + tid;
            if (e < 3042) {
                unsigned lr = (unsigned)e / 39u;
                int lc = (int)((unsigned)e - lr * 39u) * 2;
                int rr = reflect_idx(O0r + (int)lr, N0);
                int c0 = reflect_idx(O0c + lc, N0);
                int c1 = reflect_idx(O0c + lc + 1, N0);
                const float* pr = p + ibase + (size_t)rr * N0;
                const float* tr = t + ibase + (size_t)rr * N0;
                *(float2*)(s_in + lr * S0 + lc) =
                    make_float2(pr[c0] - tr[c0], pr[c1] - tr[c1]);
            }
        }
    }
    __syncthreads();

    // ---- stage 1: L1 = DWT(diff). 38 rows x 19 col-pairs = 722 units, linear ----
#pragma unroll
    for (int it = 0; it < 3; ++it) {
        int e = it * 256 + tid;
        if (e < 722) {
            unsigned lr = (unsigned)e / 19u;
            int lc = (int)((unsigned)e - lr * 19u) * 2;
            float o[2][4];
            dwt4_pair(s_in, (int)(2u * lr) * S0 + 2 * lc, S0, o);
            int slot = (int)lr * S1 + lc;
#pragma unroll
            for (int b = 0; b < 4; ++b)
                *(float2*)(s_l1 + b * P1 + slot) = make_float2(o[0][b], o[1][b]);
        }
    }
    __syncthreads();
    if (edge1) {  // patch boundary slots: slot(r,c) <- slot(reflect r, reflect c)
        for (int it = 0; it < 6; ++it) {
            int e = it * 256 + tid;
            if (e < P1) {
                unsigned lr = (unsigned)e / 38u;
                unsigned lc = (unsigned)e - lr * 38u;
                int sr = reflect_idx(O1r + (int)lr, N1) - O1r;
                int sc = reflect_idx(O1c + (int)lc, N1) - O1c;
                if ((sr != (int)lr || sc != (int)lc) &&
                    (unsigned)sr < 38u && (unsigned)sc < 38u) {
                    int dst = (int)lr * S1 + (int)lc;
                    int src = sr * S1 + sc;
#pragma unroll
                    for (int b = 0; b < 4; ++b) s_l1[b * P1 + dst] = s_l1[b * P1 + src];
                }
            }
        }
        __syncthreads();
    }

    // ---- stage 2: L2 = DWT(L1). 4 bands x 18 rows x 9 col-pairs = 648 units ----
#pragma unroll
    for (int it = 0; it < 3; ++it) {
        int e = it * 256 + tid;
        if (e < 648) {
            unsigned band = (unsigned)e / 162u;
            unsigned rem = (unsigned)e - band * 162u;
            unsigned lr = rem / 9u;
            int lc = (int)(rem - lr * 9u) * 2;
            float o[2][4];
            dwt4_pair(s_l1 + band * P1, (int)(2u * lr) * S1 + 2 * lc, S1, o);
            int slot = (int)lr * S2 + lc;
#pragma unroll
            for (int f = 0; f < 4; ++f)
                *(float2*)(s_l2 + (band * 4 + f) * P2 + slot) =
                    make_float2(o[0][f], o[1][f]);
        }
    }
    __syncthreads();
    if (edge2) {
        for (int it = 0; it < 2; ++it) {
            int e = it * 256 + tid;
            if (e < 324) {
                unsigned lr = (unsigned)e / 18u;
                unsigned lc = (unsigned)e - lr * 18u;
                int sr = reflect_idx(O2r + (int)lr, N2) - O2r;
                int sc = reflect_idx(O2c + (int)lc, N2) - O2c;
                if ((sr != (int)lr || sc != (int)lc) &&
                    (unsigned)sr < 18u && (unsigned)sc < 18u) {
                    int dst = (int)lr * S2 + (int)lc;
                    int src = sr * S2 + sc;
#pragma unroll
                    for (int pb = 0; pb < 16; ++pb)
                        s_l2[pb * P2 + dst] = s_l2[pb * P2 + src];
                }
            }
        }
        __syncthreads();
    }

    // ---- stage 3: L3 = DWT(L2), square + weight. 16 planes x 8 rows x 4 pairs ----
    float local = 0.f;
#pragma unroll
    for (int it = 0; it < 2; ++it) {
        int e = it * 256 + tid;  // < 512
        int b2 = e >> 5;
        int rem = e & 31;
        int pi = rem >> 2;
        int pj = (rem & 3) * 2;
        float o[2][4];
        dwt4_pair(s_l2 + b2 * P2, (2 * pi) * S2 + 2 * pj, S2, o);
        float w0 = (b2 == 0) ? 0.5f : 1.0f;
        bool rok = (A + pi < N3);
#pragma unroll
        for (int q = 0; q < 2; ++q) {
            if (rok && (B + pj + q < N3)) {
                local += w0 * o[q][0] * o[q][0] + o[q][1] * o[q][1] +
                         o[q][2] * o[q][2] + o[q][3] * o[q][3];
            }
        }
    }

    // block reduction: 256 threads = 4 waves, one atomic per block
#pragma unroll
    for (int off = 32; off > 0; off >>= 1) local += __shfl_down(local, off, 64);
    __shared__ float wsum[4];
    int wave = tid >> 6;
    if ((tid & 63) == 0) wsum[wave] = local;
    __syncthreads();
    if (tid == 0) {
        float s = (wsum[0] + wsum[1] + wsum[2] + wsum[3]) * inv_den;
        atomicAdd(out_sum, s);
    }
}

extern "C" void kernel_launch(void* const* d_in, const int* in_sizes, int n_in,
                              void* d_out, int out_size, void* d_ws, size_t ws_size,
                              hipStream_t stream) {
    const float* preds = (const float*)d_in[0];
    const float* targets = (const float*)d_in[1];
    float* out = (float*)d_out;

    hipMemsetAsync(d_out, 0, sizeof(float), stream);

    const float inv_den = 1.0f / (192.0f * 66.0f * 66.0f);
    const int nblk = 192 * 9 * 9;  // 15552, divisible by 8

    k_wpt_fused<<<dim3(nblk), dim3(256), 0, stream>>>(preds, targets, out, inv_den);
}